// Round 10
// baseline (26.771 us; speedup 1.0000x reference)
//
#include <hip/hip_runtime.h>
#include <math.h>

// CapLayer fused, R10 (= R9 + vectorized x preload + blocked u/squash).
// Factorized routing, pred never materialized:
//   y[g,k] = sum_{i in g} e_i x[k,i]; s[d] = sum Wk[g,k,d] y[g,k] (+bias row)
//   u[g,k] = beta sum_d s[d] Wk[g,k,d]; b_i += sum_k u[g,k] x[k,i]
// NT=128, 4 lanes/group. Lane c owns s in {4c..4c+3, 16+4c..19+4c, 32+c}
// -> x preload is 2 float4 + 1 scalar per k (24 coalesced loads vs 72
// scattered scalars in R9). u/ssq blocked over slds float4s: s16[16] block
// eliminated (~16 VGPR). NO launch_bounds min-waves (R2/R3/R7 spill lesson).

#define G_    32
#define J_    10
#define D_    16
#define NT_   128
#define GSW_  148
#define YS_   12

__global__ __launch_bounds__(NT_) void caps_route_kernel(
    const float* __restrict__ x,     // (b, g*8+k, s) flat b*9216 + g*288 + k*36 + s
    const float* __restrict__ Wt,    // (g, j*16+d, k) flat g*1280 + (j*16+d)*8 + k
    const float* __restrict__ bias,  // g*160 + j*16 + d
    float* __restrict__ out)         // (b, j, d)
{
    const int B = blockIdx.x, nwg = gridDim.x;
    const int bj = ((nwg & 7) == 0) ? (B & 7) * (nwg >> 3) + (B >> 3) : B;
    const int b = bj / J_, j = bj - b * J_;
    const int t = threadIdx.x;
    const int lane = t & 63, wid = t >> 6;
    const int g = t >> 2, c = t & 3;     // group 0..31, 4 lanes/group

    __shared__ float Wk[G_ * GSW_];              // ~18.5 KB, [g][k][d] (+bias k=8)
    __shared__ __align__(16) float ylds[G_ * YS_];
    __shared__ __align__(16) float slds[D_];
    __shared__ float dsum[2];

    // ---- x preload: 2 aligned float4 + 1 scalar per k, coalesced ----
    float xv[8][9];
    {
        const float* xb = x + (size_t)b * 9216 + (size_t)g * 288 + 4 * c;
        #pragma unroll
        for (int k = 0; k < 8; ++k) {
            const float4 a0 = *(const float4*)(xb + k * 36);
            const float4 a1 = *(const float4*)(xb + k * 36 + 16);
            xv[k][0] = a0.x; xv[k][1] = a0.y; xv[k][2] = a0.z; xv[k][3] = a0.w;
            xv[k][4] = a1.x; xv[k][5] = a1.y; xv[k][6] = a1.z; xv[k][7] = a1.w;
            xv[k][8] = xb[k * 36 + 32 - 3 * c];   // = row + 32 + c
        }
    }

    // ---- stage Wk transposed ([g][k][d]) + bias as k=8 row ----
    #pragma unroll
    for (int rr = 0; rr < 4; ++rr) {
        const int idx = t + rr * NT_;
        const int gg = idx >> 4, d = idx & 15;
        const float* src = Wt + (size_t)gg * 1280 + j * 128 + d * 8;
        const float4 a0 = *(const float4*)(src);
        const float4 a1 = *(const float4*)(src + 4);
        float* dst = Wk + gg * GSW_ + d;
        dst[0]   = a0.x; dst[16]  = a0.y; dst[32]  = a0.z; dst[48]  = a0.w;
        dst[64]  = a1.x; dst[80]  = a1.y; dst[96]  = a1.z; dst[112] = a1.w;
        dst[128] = bias[gg * 160 + j * 16 + d];
    }
    __syncthreads();

    float b_loc[9] = {0.f,0.f,0.f,0.f,0.f,0.f,0.f,0.f,0.f};
    const float EPS = 2.220446049250313e-16f;

    #pragma unroll 1
    for (int it = 0; it < 3; ++it) {
        // ---- e-weighted x sums (per-thread partial over its 9 s's) ----
        float yp[8] = {0.f,0.f,0.f,0.f,0.f,0.f,0.f,0.f};
        float esum;
        if (it == 0) {
            #pragma unroll
            for (int q = 0; q < 9; ++q) {
                #pragma unroll
                for (int k = 0; k < 8; ++k) yp[k] += xv[k][q];
            }
            esum = 9.f;
        } else {
            esum = 0.f;
            #pragma unroll
            for (int q = 0; q < 9; ++q) {
                const float e = __expf(b_loc[q]);
                esum += e;
                #pragma unroll
                for (int k = 0; k < 8; ++k) yp[k] += e * xv[k][q];
            }
        }
        // 4-lane group reduce -> y[g,k], C_g
        #pragma unroll
        for (int k = 0; k < 8; ++k) {
            yp[k] += __shfl_xor(yp[k], 1);
            yp[k] += __shfl_xor(yp[k], 2);
        }
        esum += __shfl_xor(esum, 1);
        esum += __shfl_xor(esum, 2);
        if (c == 0) {
            float4 w0; w0.x = yp[0]; w0.y = yp[1]; w0.z = yp[2]; w0.w = yp[3];
            float4 w1; w1.x = yp[4]; w1.y = yp[5]; w1.z = yp[6]; w1.w = yp[7];
            *(float4*)(ylds + g * YS_)     = w0;
            *(float4*)(ylds + g * YS_ + 4) = w1;
            ylds[g * YS_ + 8] = esum;            // C_g
        }
        // denom: bits 2..5 butterfly sums the wave's 16 distinct groups once each
        float ws = esum;
        ws += __shfl_xor(ws, 4);  ws += __shfl_xor(ws, 8);
        ws += __shfl_xor(ws, 16); ws += __shfl_xor(ws, 32);
        if (lane == 0) dsum[wid] = ws;
        __syncthreads();                          // barrier 1
        const float denom = dsum[0] + dsum[1];

        // ---- s[d] = sum_{g,k} Wk[g][k][d] * y[g][k]  (incl. bias*C_g) ----
        {
            const int d = t >> 3, gg0 = t & 7;
            float sp = 0.f;
            #pragma unroll
            for (int gi = 0; gi < 4; ++gi) {
                const int gg = gg0 + 8 * gi;
                const float* wr = Wk + gg * GSW_ + d;
                const float* yr = ylds + gg * YS_;
                const float4 y0 = *(const float4*)(yr);
                const float4 y1 = *(const float4*)(yr + 4);
                const float  y8 = yr[8];
                const float sp0 = wr[0]  * y0.x + wr[16]  * y0.y + wr[32] * y0.z + wr[48]  * y0.w;
                const float sp1 = wr[64] * y1.x + wr[80]  * y1.y + wr[96] * y1.z + wr[112] * y1.w;
                sp += sp0 + sp1 + wr[128] * y8;
            }
            sp += __shfl_xor(sp, 1); sp += __shfl_xor(sp, 2); sp += __shfl_xor(sp, 4);
            if ((t & 7) == 0) slds[d] = sp;
        }
        __syncthreads();                          // barrier 2

        if (it < 2) {
            // ---- blocked squash + u[g,k] partial dots (4 s-values live) ----
            float ssq = 0.f, ua = 0.f, ub = 0.f, u8v = 0.f;
            const float* wgc = Wk + g * GSW_;
            #pragma unroll
            for (int m = 0; m < 4; ++m) {
                const float4 s4 = ((const float4*)slds)[m];
                ssq += s4.x * s4.x + s4.y * s4.y + s4.z * s4.z + s4.w * s4.w;
                const float* wa = wgc + c * 16 + 4 * m;
                const float* wb = wgc + (c + 4) * 16 + 4 * m;
                const float* w8 = wgc + 128 + 4 * m;
                ua  += s4.x * wa[0] + s4.y * wa[1] + s4.z * wa[2] + s4.w * wa[3];
                ub  += s4.x * wb[0] + s4.y * wb[1] + s4.z * wb[2] + s4.w * wb[3];
                u8v += s4.x * w8[0] + s4.y * w8[1] + s4.z * w8[2] + s4.w * w8[3];
            }
            const float alpha = 1.f / denom;
            const float n2    = ssq * alpha * alpha;
            const float nrm   = sqrtf(n2);
            const float coeff = (n2 / (1.f + n2)) / (nrm + EPS);
            const float beta  = alpha * coeff;
            ua *= beta; ub *= beta; u8v *= beta;

            // gather u[0..7] across the 4-lane group (6 shfl)
            const float p1a = __shfl_xor(ua, 1);
            const float p1b = __shfl_xor(ub, 1);
            const bool  o1  = (c & 1) != 0;
            const float v0 = o1 ? p1a : ua;
            const float v1 = o1 ? ua  : p1a;
            const float v4 = o1 ? p1b : ub;
            const float v5 = o1 ? ub  : p1b;
            const float q0 = __shfl_xor(v0, 2);
            const float q1 = __shfl_xor(v1, 2);
            const float q4 = __shfl_xor(v4, 2);
            const float q5 = __shfl_xor(v5, 2);
            const bool  o2 = (c & 2) != 0;
            float u[8];
            u[0] = o2 ? q0 : v0;  u[1] = o2 ? q1 : v1;
            u[2] = o2 ? v0 : q0;  u[3] = o2 ? v1 : q1;
            u[4] = o2 ? q4 : v4;  u[5] = o2 ? q5 : v5;
            u[6] = o2 ? v4 : q4;  u[7] = o2 ? v5 : q5;
            // ---- b_i += u . x_i + u_bias ----
            #pragma unroll
            for (int q = 0; q < 9; ++q) {
                float acc = u8v;
                #pragma unroll
                for (int k = 0; k < 8; ++k) acc += u[k] * xv[k][q];
                b_loc[q] += acc;
            }
        } else {
            // ---- final squash + output ----
            float ssq = 0.f;
            #pragma unroll
            for (int m = 0; m < 4; ++m) {
                const float4 s4 = ((const float4*)slds)[m];
                ssq += s4.x * s4.x + s4.y * s4.y + s4.z * s4.z + s4.w * s4.w;
            }
            const float alpha = 1.f / denom;
            const float n2    = ssq * alpha * alpha;
            const float nrm   = sqrtf(n2);
            const float coeff = (n2 / (1.f + n2)) / (nrm + EPS);
            const float beta  = alpha * coeff;
            if (t < D_) out[(size_t)bj * D_ + t] = slds[t] * beta;
        }
    }
}

extern "C" void kernel_launch(void* const* d_in, const int* in_sizes, int n_in,
                              void* d_out, int out_size, void* d_ws, size_t ws_size,
                              hipStream_t stream) {
    const float* x    = (const float*)d_in[0];
    const float* Wt   = (const float*)d_in[1];
    const float* bias = (const float*)d_in[2];
    float* out        = (float*)d_out;

    const int bs = in_sizes[0] / 9216;   // 256
    dim3 grid(bs * J_);                  // 2560
    dim3 block(NT_);
    caps_route_kernel<<<grid, block, 0, stream>>>(x, Wt, bias, out);
}